// Round 6
// baseline (808.379 us; speedup 1.0000x reference)
//
#include <hip/hip_runtime.h>
#include <math.h>

#define NB 4096
#define IN_D 230
#define DM 256
#define NL 12
#define DST 16
#define DI 512
#define DTR 16
#define XPN 48
#define XST 516   // xcs/szs row stride (shorts): 258 dw, 4-row stride = 8 banks
#define HST 264   // hs row stride

typedef __attribute__((ext_vector_type(8))) short short8;
typedef __attribute__((ext_vector_type(4))) float floatx4;

__device__ __forceinline__ float silu_f(float x) { return x / (1.0f + expf(-x)); }
__device__ __forceinline__ float softplus_f(float x) { return (x > 20.0f) ? x : log1pf(expf(x)); }
__device__ __forceinline__ short f2bf(float x) {
    union { float f; unsigned u; } v; v.f = x;
    unsigned r = v.u + 0x7fff + ((v.u >> 16) & 1);
    return (short)(r >> 16);
}
__device__ __forceinline__ float bf2f(short s) {
    union { unsigned u; float f; } v; v.u = ((unsigned)(unsigned short)s) << 16;
    return v.f;
}
__device__ __forceinline__ float bf2f_lo(unsigned u) {
    union { unsigned u; float f; } v; v.u = u << 16; return v.f;
}
__device__ __forceinline__ float bf2f_hi(unsigned u) {
    union { unsigned u; float f; } v; v.u = u & 0xffff0000u; return v.f;
}

// ---------- conversion kernels (once per call) ----------

__global__ __launch_bounds__(256) void conv_x(const float* __restrict__ x, short* __restrict__ xp) {
    int idx = blockIdx.x * 256 + threadIdx.x;
    int r = idx >> 8, k = idx & 255;
    float v = (k < IN_D) ? x[(size_t)r * IN_D + k] : 0.0f;
    xp[idx] = f2bf(v);
}

// src [K x N] fp32 -> dst [Np x Kp] bf16 (dst[n][k]=src[k][n], zero-pad)
__global__ __launch_bounds__(256) void conv_wt_t(const float* __restrict__ src0, short* __restrict__ dst0,
                                                 int K, int N, int Kp, int Np) {
    const float* src = src0 + (size_t)blockIdx.z * K * N;
    short* dst = dst0 + (size_t)blockIdx.z * Np * Kp;
    __shared__ float t[64][65];
    const int k0 = blockIdx.x * 64, n0 = blockIdx.y * 64;
    const int r = threadIdx.x >> 6, c = threadIdx.x & 63;
#pragma unroll
    for (int i = 0; i < 16; i++) {
        int kk = k0 + i * 4 + r;
        int nn = n0 + c;
        float v = (kk < K && nn < N) ? src[(size_t)kk * N + nn] : 0.0f;
        t[i * 4 + r][c] = v;
    }
    __syncthreads();
#pragma unroll
    for (int i = 0; i < 16; i++) {
        int nn = n0 + i * 4 + r;
        int kk = k0 + c;
        dst[(size_t)nn * Kp + kk] = f2bf(t[c][i * 4 + r]);
    }
}

// dt_w [NL][16][512] fp32 -> dtwT [NL][512][16] fp32
__global__ __launch_bounds__(256) void conv_dtw(const float* __restrict__ src, float* __restrict__ dst) {
    int l = blockIdx.y;
    int idx = blockIdx.x * 256 + threadIdx.x;
    int d = idx >> 4, r = idx & 15;
    dst[(size_t)l * DI * DTR + idx] = src[(size_t)l * DTR * DI + r * DI + d];
}

// ---------- the whole network, fused: 256 wgs x 16 rows, 1024 threads ----------
__global__ __launch_bounds__(1024) void mamba_all(
    const short* __restrict__ xpad, const short* __restrict__ WiT,
    const float* __restrict__ bi,
    const short* __restrict__ ipT, const short* __restrict__ opT,
    const short* __restrict__ xpT, const float* __restrict__ dtwT,
    const float* __restrict__ conv_w, const float* __restrict__ conv_b,
    const float* __restrict__ dt_b, const float* __restrict__ Dp,
    const float* __restrict__ Wo, const float* __restrict__ bo,
    float* __restrict__ out)
{
    __shared__ short hs[16 * HST];
    __shared__ short xcs[16 * XST];    // xc, then y in place
    __shared__ short szs[16 * XST];
    __shared__ float dbls[16 * 68];
    __shared__ float sbc[16];

    const int tid = threadIdx.x;
    const int w = tid >> 6, lane = tid & 63;
    const int q = lane >> 4, m16 = lane & 15;
    const int rb = blockIdx.x * 16;
    const int b = blockIdx.x;
    // per-block rotation: decorrelate concurrent CUs' weight streams
    const int rot  = (((b >> 3) + (b & 7) * 2) & 15);
    const int ks8  = (((b >> 3) + (b & 7)) & 7);        // K rotation, 8-step loops
    const int ks16 = (((b >> 3) * 3 + (b & 7)) & 15);   // K rotation, 16-step loops

    // stage 0: h = xpad @ WiT + bi
    {
        floatx4 acc = (floatx4){0.f, 0.f, 0.f, 0.f};
        const short* Ap = xpad + (size_t)(rb + m16) * DM + q * 8;
        const short* Bp = WiT + (size_t)(w * 16 + m16) * DM + q * 8;
#pragma unroll
        for (int kk = 0; kk < DM; kk += 32) {
            short8 a = *(const short8*)(Ap + kk);
            short8 bb = *(const short8*)(Bp + kk);
            acc = __builtin_amdgcn_mfma_f32_16x16x32_bf16(a, bb, acc, 0, 0, 0);
        }
        int col = w * 16 + m16;
#pragma unroll
        for (int r = 0; r < 4; r++)
            hs[(q * 4 + r) * HST + col] = f2bf(acc[r] + bi[col]);
    }
    __syncthreads();

    for (int l = 0; l < NL; l++) {
        const short* ip = ipT + (size_t)l * 2 * DI * DM;
        const short* xp = xpT + (size_t)l * 64 * DI;
        const short* op = opT + (size_t)l * DM * DI;
        const float* dw = dtwT + (size_t)l * DI * DTR;
        const float* cw = conv_w + (size_t)l * DI * 4;
        const float* cb = conv_b + (size_t)l * DI;
        const float* db = dt_b + (size_t)l * DI;
        const float* Dv = Dp + (size_t)l * DI;

        // stage 1: xz = h @ in_projT  (wave handles rotated frag f of 16; 64 cols)
        {
            const int f = (w + rot) & 15;
            floatx4 acc[4];
#pragma unroll
            for (int t = 0; t < 4; t++) acc[t] = (floatx4){0.f, 0.f, 0.f, 0.f};
            const short* Bp = ip + (size_t)(f * 64 + m16) * DM + q * 8;
            const short* Ar = hs + m16 * HST + q * 8;
#pragma unroll
            for (int i = 0; i < 8; i++) {
                int kk = ((ks8 + i) & 7) * 32;
                short8 a = *(const short8*)(Ar + kk);
                short8 bb[4];
#pragma unroll
                for (int t = 0; t < 4; t++) bb[t] = *(const short8*)(Bp + (size_t)t * 16 * DM + kk);
#pragma unroll
                for (int t = 0; t < 4; t++)
                    acc[t] = __builtin_amdgcn_mfma_f32_16x16x32_bf16(a, bb[t], acc[t], 0, 0, 0);
            }
            if (f < 8) {
#pragma unroll
                for (int t = 0; t < 4; t++)
#pragma unroll
                    for (int r = 0; r < 4; r++) {
                        int col = f * 64 + t * 16 + m16;
                        float v = silu_f(acc[t][r] * cw[col * 4 + 3] + cb[col]);
                        xcs[(q * 4 + r) * XST + col] = f2bf(v);
                    }
            } else {
#pragma unroll
                for (int t = 0; t < 4; t++)
#pragma unroll
                    for (int r = 0; r < 4; r++) {
                        int col = (f - 8) * 64 + t * 16 + m16;
                        szs[(q * 4 + r) * XST + col] = f2bf(silu_f(acc[t][r]));
                    }
            }
        }
        __syncthreads();

        // stage 2: dbl = xc @ x_projT  (waves 0..3, rotated frag, 2 accumulators)
        if (w < 4) {
            const int f2 = (w + rot) & 3;
            floatx4 a0 = (floatx4){0.f, 0.f, 0.f, 0.f};
            floatx4 a1 = (floatx4){0.f, 0.f, 0.f, 0.f};
            const short* Bp = xp + (size_t)(f2 * 16 + m16) * DI + q * 8;
            const short* Ar = xcs + m16 * XST + q * 8;
#pragma unroll
            for (int i = 0; i < 16; i += 2) {
                int k0 = ((ks16 + i) & 15) * 32;
                int k1 = ((ks16 + i + 1) & 15) * 32;
                short8 av0 = *(const short8*)(Ar + k0);
                short8 bv0 = *(const short8*)(Bp + k0);
                short8 av1 = *(const short8*)(Ar + k1);
                short8 bv1 = *(const short8*)(Bp + k1);
                a0 = __builtin_amdgcn_mfma_f32_16x16x32_bf16(av0, bv0, a0, 0, 0, 0);
                a1 = __builtin_amdgcn_mfma_f32_16x16x32_bf16(av1, bv1, a1, 0, 0, 0);
            }
            a0 = a0 + a1;
#pragma unroll
            for (int r = 0; r < 4; r++)
                dbls[(q * 4 + r) * 68 + f2 * 16 + m16] = a0[r];
        }
        __syncthreads();

        // bc[row] = dbl[row,16:32].dbl[row,32:48]  (256 threads, shuffle-reduce)
        if (tid < 256) {
            int row = tid >> 4, s = tid & 15;
            float p = dbls[row * 68 + DTR + s] * dbls[row * 68 + DTR + DST + s];
            p += __shfl_xor(p, 1);
            p += __shfl_xor(p, 2);
            p += __shfl_xor(p, 4);
            p += __shfl_xor(p, 8);
            if (s == 0) sbc[row] = p;
        }
        __syncthreads();

        // stage 3: y = (softplus(dt)*bc + D) * xc * sz  (d-pair per thread, 4 rows)
        {
            const int pair = tid & 255;          // d0 = 2*pair
            const int d0 = pair * 2;
            const int r0 = (tid >> 8) * 4;
            float wv0[DTR], wv1[DTR];
            const float* wp = dw + (size_t)d0 * DTR;
#pragma unroll
            for (int r = 0; r < DTR; r++) { wv0[r] = wp[r]; wv1[r] = wp[DTR + r]; }
            const float db0 = db[d0], db1 = db[d0 + 1];
            const float dv0 = Dv[d0], dv1 = Dv[d0 + 1];
#pragma unroll
            for (int i = 0; i < 4; i++) {
                int row = r0 + i;
                float a0 = db0, a1 = db1;
#pragma unroll
                for (int r = 0; r < DTR; r++) {
                    float dl = dbls[row * 68 + r];
                    a0 += dl * wv0[r];
                    a1 += dl * wv1[r];
                }
                float bc = sbc[row];
                int offs = (row * XST + d0) >> 1;      // dword index
                unsigned xcv = ((const unsigned*)xcs)[offs];
                unsigned szv = ((const unsigned*)szs)[offs];
                float y0 = (softplus_f(a0) * bc + dv0) * bf2f_lo(xcv) * bf2f_lo(szv);
                float y1 = (softplus_f(a1) * bc + dv1) * bf2f_hi(xcv) * bf2f_hi(szv);
                unsigned outv = ((unsigned)(unsigned short)f2bf(y0)) |
                                (((unsigned)(unsigned short)f2bf(y1)) << 16);
                ((unsigned*)xcs)[offs] = outv;
            }
        }
        __syncthreads();

        // stage 4: h = y @ out_projT  (wave handles rotated col-frag of 16; 2 accs)
        {
            const int f4 = (w + rot) & 15;
            floatx4 a0 = (floatx4){0.f, 0.f, 0.f, 0.f};
            floatx4 a1 = (floatx4){0.f, 0.f, 0.f, 0.f};
            const short* Bp = op + (size_t)(f4 * 16 + m16) * DI + q * 8;
            const short* Ar = xcs + m16 * XST + q * 8;
#pragma unroll
            for (int i = 0; i < 16; i += 2) {
                int k0 = ((ks16 + i) & 15) * 32;
                int k1 = ((ks16 + i + 1) & 15) * 32;
                short8 av0 = *(const short8*)(Ar + k0);
                short8 bv0 = *(const short8*)(Bp + k0);
                short8 av1 = *(const short8*)(Ar + k1);
                short8 bv1 = *(const short8*)(Bp + k1);
                a0 = __builtin_amdgcn_mfma_f32_16x16x32_bf16(av0, bv0, a0, 0, 0, 0);
                a1 = __builtin_amdgcn_mfma_f32_16x16x32_bf16(av1, bv1, a1, 0, 0, 0);
            }
            a0 = a0 + a1;
            int col = f4 * 16 + m16;
#pragma unroll
            for (int r = 0; r < 4; r++)
                hs[(q * 4 + r) * HST + col] = f2bf(a0[r]);
        }
        __syncthreads();
    }

    // final: wave w reduces row w
    {
        float s = 0.0f;
#pragma unroll
        for (int j = 0; j < 4; j++)
            s += bf2f(hs[w * HST + lane * 4 + j]) * Wo[lane * 4 + j];
#pragma unroll
        for (int off = 32; off > 0; off >>= 1) s += __shfl_down(s, off);
        if (lane == 0) out[rb + w] = s + bo[0];
    }
}

extern "C" void kernel_launch(void* const* d_in, const int* in_sizes, int n_in,
                              void* d_out, int out_size, void* d_ws, size_t ws_size,
                              hipStream_t stream)
{
    const float* x       = (const float*)d_in[0];
    const float* Wi      = (const float*)d_in[1];
    const float* bi      = (const float*)d_in[2];
    const float* in_proj = (const float*)d_in[3];
    const float* conv_w  = (const float*)d_in[4];
    const float* conv_b  = (const float*)d_in[5];
    const float* x_proj  = (const float*)d_in[6];
    const float* dt_w    = (const float*)d_in[7];
    const float* dt_b    = (const float*)d_in[8];
    // d_in[9] = A_log: dead (L==1, h0==0)
    const float* Dp      = (const float*)d_in[10];
    const float* out_pw  = (const float*)d_in[11];
    const float* Wo      = (const float*)d_in[12];
    const float* bo      = (const float*)d_in[13];

    short* ws   = (short*)d_ws;
    short* xpad = ws;                                   // 4096*256
    short* WiT  = xpad + (size_t)NB * DM;               // 256*256
    short* ipT  = WiT + (size_t)DM * DM;                // 12*1024*256
    short* opT  = ipT + (size_t)NL * 2 * DI * DM;       // 12*256*512
    short* xpT  = opT + (size_t)NL * DM * DI;           // 12*64*512
    float* dtwT = (float*)(xpT + (size_t)NL * 64 * DI); // 12*512*16 fp32

    dim3 blk(256);

    conv_x<<<dim3(NB * DM / 256), blk, 0, stream>>>(x, xpad);
    conv_wt_t<<<dim3(4, 4, 1), blk, 0, stream>>>(Wi, WiT, IN_D, DM, DM, DM);
    conv_wt_t<<<dim3(4, 16, NL), blk, 0, stream>>>(in_proj, ipT, DM, 2 * DI, DM, 2 * DI);
    conv_wt_t<<<dim3(8, 4, NL), blk, 0, stream>>>(out_pw, opT, DI, DM, DI, DM);
    conv_wt_t<<<dim3(8, 1, NL), blk, 0, stream>>>(x_proj, xpT, DI, XPN, DI, 64);
    conv_dtw<<<dim3(DI * DTR / 256, NL), blk, 0, stream>>>(dt_w, dtwT);

    mamba_all<<<dim3(NB / 16), dim3(1024), 0, stream>>>(
        xpad, WiT, bi, ipT, opT, xpT, dtwT,
        conv_w, conv_b, dt_b, Dp, Wo, bo, (float*)d_out);
}

// Round 7
// 597.913 us; speedup vs baseline: 1.3520x; 1.3520x over previous
//
#include <hip/hip_runtime.h>
#include <math.h>

#define NB 4096
#define IN_D 230
#define DM 256
#define NL 12
#define DST 16
#define DI 512
#define DTR 16
#define XPN 48
#define XST 516   // xcs/szs row stride (shorts)
#define HST 264   // hs row stride

typedef __attribute__((ext_vector_type(8))) short short8;
typedef __attribute__((ext_vector_type(4))) float floatx4;

__device__ __forceinline__ float silu_f(float x) { return x / (1.0f + expf(-x)); }
__device__ __forceinline__ float softplus_f(float x) { return (x > 20.0f) ? x : log1pf(expf(x)); }
__device__ __forceinline__ short f2bf(float x) {
    union { float f; unsigned u; } v; v.f = x;
    unsigned r = v.u + 0x7fff + ((v.u >> 16) & 1);
    return (short)(r >> 16);
}
__device__ __forceinline__ float bf2f(short s) {
    union { unsigned u; float f; } v; v.u = ((unsigned)(unsigned short)s) << 16;
    return v.f;
}

// ---------- conversion kernels (once per call) ----------

__global__ __launch_bounds__(256) void conv_x(const float* __restrict__ x, short* __restrict__ xp) {
    int idx = blockIdx.x * 256 + threadIdx.x;
    int r = idx >> 8, k = idx & 255;
    float v = (k < IN_D) ? x[(size_t)r * IN_D + k] : 0.0f;
    xp[idx] = f2bf(v);
}

// src [K x N] fp32 -> dst [Np x Kp] bf16 (dst[n][k]=src[k][n], zero-pad)
__global__ __launch_bounds__(256) void conv_wt_t(const float* __restrict__ src0, short* __restrict__ dst0,
                                                 int K, int N, int Kp, int Np) {
    const float* src = src0 + (size_t)blockIdx.z * K * N;
    short* dst = dst0 + (size_t)blockIdx.z * Np * Kp;
    __shared__ float t[64][65];
    const int k0 = blockIdx.x * 64, n0 = blockIdx.y * 64;
    const int r = threadIdx.x >> 6, c = threadIdx.x & 63;
#pragma unroll
    for (int i = 0; i < 16; i++) {
        int kk = k0 + i * 4 + r;
        int nn = n0 + c;
        float v = (kk < K && nn < N) ? src[(size_t)kk * N + nn] : 0.0f;
        t[i * 4 + r][c] = v;
    }
    __syncthreads();
#pragma unroll
    for (int i = 0; i < 16; i++) {
        int nn = n0 + i * 4 + r;
        int kk = k0 + c;
        dst[(size_t)nn * Kp + kk] = f2bf(t[c][i * 4 + r]);
    }
}

// dt_w [NL][16][512] fp32 -> dtwT [NL][512][16] fp32
__global__ __launch_bounds__(256) void conv_dtw(const float* __restrict__ src, float* __restrict__ dst) {
    int l = blockIdx.y;
    int idx = blockIdx.x * 256 + threadIdx.x;
    int d = idx >> 4, r = idx & 15;
    dst[(size_t)l * DI * DTR + idx] = src[(size_t)l * DTR * DI + r * DI + d];
}

// ---------- the whole network, fused: 256 wgs x 16 rows, 1024 threads ----------
__global__ __launch_bounds__(1024, 4) void mamba_all(
    const short* __restrict__ xpad, const short* __restrict__ WiT,
    const float* __restrict__ bi,
    const short* __restrict__ ipT, const short* __restrict__ opT,
    const short* __restrict__ xpT, const float* __restrict__ dtwT,
    const float* __restrict__ conv_w, const float* __restrict__ conv_b,
    const float* __restrict__ dt_b, const float* __restrict__ Dp,
    const float* __restrict__ Wo, const float* __restrict__ bo,
    float* __restrict__ out)
{
    __shared__ short hs[16 * HST];
    __shared__ short xcs[16 * XST];    // xc, then y in place
    __shared__ short szs[16 * XST];
    __shared__ float dbls[16 * 68];
    __shared__ float sbc[16];

    const int tid = threadIdx.x;
    const int w = tid >> 6, lane = tid & 63;
    const int q = lane >> 4, m16 = lane & 15;
    const int rb = blockIdx.x * 16;

    // stage 0: h = xpad @ WiT + bi
    {
        floatx4 acc = (floatx4){0.f, 0.f, 0.f, 0.f};
        const short* Ap = xpad + (size_t)(rb + m16) * DM + q * 8;
        const short* Bp = WiT + (size_t)(w * 16 + m16) * DM + q * 8;
#pragma unroll
        for (int kk = 0; kk < DM; kk += 32) {
            short8 a = *(const short8*)(Ap + kk);
            short8 bb = *(const short8*)(Bp + kk);
            acc = __builtin_amdgcn_mfma_f32_16x16x32_bf16(a, bb, acc, 0, 0, 0);
        }
        int col = w * 16 + m16;
#pragma unroll
        for (int r = 0; r < 4; r++)
            hs[(q * 4 + r) * HST + col] = f2bf(acc[r] + bi[col]);
    }
    __syncthreads();

    for (int l = 0; l < NL; l++) {
        const short* ip = ipT + (size_t)l * 2 * DI * DM;
        const short* xp = xpT + (size_t)l * 64 * DI;
        const short* op = opT + (size_t)l * DM * DI;
        const float* dw = dtwT + (size_t)l * DI * DTR;
        const float* cw = conv_w + (size_t)l * DI * 4;
        const float* cb = conv_b + (size_t)l * DI;
        const float* db = dt_b + (size_t)l * DI;
        const float* Dv = Dp + (size_t)l * DI;

        // stage 1: xz = h @ in_projT — wave w owns cols [w*64, w*64+64);
        // register double-buffer: 16 frag-loads in flight at prologue, 8 steady.
        {
            const short* Bp = ip + (size_t)(w * 64 + m16) * DM + q * 8;
            const short* Ar = hs + m16 * HST + q * 8;
            short8 buf[2][8];
#pragma unroll
            for (int t = 0; t < 4; t++) {
                buf[0][t]     = *(const short8*)(Bp + (size_t)t * 16 * DM);
                buf[0][4 + t] = *(const short8*)(Bp + (size_t)t * 16 * DM + 32);
            }
#pragma unroll
            for (int t = 0; t < 4; t++) {
                buf[1][t]     = *(const short8*)(Bp + (size_t)t * 16 * DM + 64);
                buf[1][4 + t] = *(const short8*)(Bp + (size_t)t * 16 * DM + 96);
            }
            floatx4 acc[4];
#pragma unroll
            for (int t = 0; t < 4; t++) acc[t] = (floatx4){0.f, 0.f, 0.f, 0.f};
#pragma unroll
            for (int jj = 0; jj < 4; jj++) {
                short8 a0 = *(const short8*)(Ar + jj * 64);
                short8 a1 = *(const short8*)(Ar + jj * 64 + 32);
#pragma unroll
                for (int t = 0; t < 4; t++)
                    acc[t] = __builtin_amdgcn_mfma_f32_16x16x32_bf16(a0, buf[jj & 1][t], acc[t], 0, 0, 0);
#pragma unroll
                for (int t = 0; t < 4; t++)
                    acc[t] = __builtin_amdgcn_mfma_f32_16x16x32_bf16(a1, buf[jj & 1][4 + t], acc[t], 0, 0, 0);
                if (jj < 2) {
#pragma unroll
                    for (int t = 0; t < 4; t++) {
                        buf[jj & 1][t]     = *(const short8*)(Bp + (size_t)t * 16 * DM + (jj * 64 + 128));
                        buf[jj & 1][4 + t] = *(const short8*)(Bp + (size_t)t * 16 * DM + (jj * 64 + 160));
                    }
                }
            }
            if (w < 8) {
#pragma unroll
                for (int t = 0; t < 4; t++)
#pragma unroll
                    for (int r = 0; r < 4; r++) {
                        int col = w * 64 + t * 16 + m16;
                        float v = silu_f(acc[t][r] * cw[col * 4 + 3] + cb[col]);
                        xcs[(q * 4 + r) * XST + col] = f2bf(v);
                    }
            } else {
#pragma unroll
                for (int t = 0; t < 4; t++)
#pragma unroll
                    for (int r = 0; r < 4; r++) {
                        int col = (w - 8) * 64 + t * 16 + m16;
                        szs[(q * 4 + r) * XST + col] = f2bf(silu_f(acc[t][r]));
                    }
            }
        }
        __syncthreads();

        // prefetch stage-4 weights (first 8 K-chunks) — hidden behind stage 2/bc/3
        const short* Op = op + (size_t)(w * 16 + m16) * DI + q * 8;
        short8 opb[8];
#pragma unroll
        for (int c = 0; c < 8; c++) opb[c] = *(const short8*)(Op + c * 32);

        // stage 2: dbl = xc @ x_projT  (waves 0..3), register double-buffer
        if (w < 4) {
            const short* Bp2 = xp + (size_t)(w * 16 + m16) * DI + q * 8;
            const short* Ar2 = xcs + m16 * XST + q * 8;
            short8 bb[2][4];
#pragma unroll
            for (int c = 0; c < 4; c++) bb[0][c] = *(const short8*)(Bp2 + c * 32);
#pragma unroll
            for (int c = 0; c < 4; c++) bb[1][c] = *(const short8*)(Bp2 + 128 + c * 32);
            floatx4 a0 = (floatx4){0.f, 0.f, 0.f, 0.f};
            floatx4 a1 = (floatx4){0.f, 0.f, 0.f, 0.f};
#pragma unroll
            for (int g = 0; g < 4; g++) {
#pragma unroll
                for (int c = 0; c < 4; c++) {
                    short8 av = *(const short8*)(Ar2 + (g * 4 + c) * 32);
                    if (c & 1) a1 = __builtin_amdgcn_mfma_f32_16x16x32_bf16(av, bb[g & 1][c], a1, 0, 0, 0);
                    else       a0 = __builtin_amdgcn_mfma_f32_16x16x32_bf16(av, bb[g & 1][c], a0, 0, 0, 0);
                }
                if (g < 2) {
#pragma unroll
                    for (int c = 0; c < 4; c++)
                        bb[g & 1][c] = *(const short8*)(Bp2 + (g * 4 + 8 + c) * 32);
                }
            }
            a0 = a0 + a1;
#pragma unroll
            for (int r = 0; r < 4; r++)
                dbls[(q * 4 + r) * 68 + w * 16 + m16] = a0[r];
        }
        __syncthreads();

        // hoisted dt_w loads (hidden behind bc + barrier)
        const int d3 = tid & 511;
        const int rh = (tid >> 9) * 8;
        float wv[DTR];
        {
            const float* wp = dw + (size_t)d3 * DTR;
#pragma unroll
            for (int r = 0; r < DTR; r++) wv[r] = wp[r];
        }
        const float db3 = db[d3], dv3 = Dv[d3];

        // bc[row] = dbl[row,16:32].dbl[row,32:48]
        if (tid < 256) {
            int row = tid >> 4, s = tid & 15;
            float p = dbls[row * 68 + DTR + s] * dbls[row * 68 + DTR + DST + s];
            p += __shfl_xor(p, 1);
            p += __shfl_xor(p, 2);
            p += __shfl_xor(p, 4);
            p += __shfl_xor(p, 8);
            if (s == 0) sbc[row] = p;
        }
        __syncthreads();

        // stage 3: y = (softplus(dt)*bc + D) * xc * sz   (1 d/thread, 8 rows)
        {
#pragma unroll
            for (int i = 0; i < 8; i++) {
                int row = rh + i;
                float a = db3;
#pragma unroll
                for (int r = 0; r < DTR; r++) a += dbls[row * 68 + r] * wv[r];
                float dt = softplus_f(a);
                int off = row * XST + d3;
                float v = (dt * sbc[row] + dv3) * bf2f(xcs[off]) * bf2f(szs[off]);
                xcs[off] = f2bf(v);
            }
        }
        __syncthreads();

        // stage 4: h = y @ out_projT — first 8 chunks prefetched, second 8 issued now
        {
            const short* Ar4 = xcs + m16 * XST + q * 8;
            short8 opb2[8];
#pragma unroll
            for (int c = 0; c < 8; c++) opb2[c] = *(const short8*)(Op + (8 + c) * 32);
            floatx4 a0 = (floatx4){0.f, 0.f, 0.f, 0.f};
            floatx4 a1 = (floatx4){0.f, 0.f, 0.f, 0.f};
#pragma unroll
            for (int c = 0; c < 8; c++) {
                short8 av = *(const short8*)(Ar4 + c * 32);
                if (c & 1) a1 = __builtin_amdgcn_mfma_f32_16x16x32_bf16(av, opb[c], a1, 0, 0, 0);
                else       a0 = __builtin_amdgcn_mfma_f32_16x16x32_bf16(av, opb[c], a0, 0, 0, 0);
            }
#pragma unroll
            for (int c = 0; c < 8; c++) {
                short8 av = *(const short8*)(Ar4 + (8 + c) * 32);
                if (c & 1) a1 = __builtin_amdgcn_mfma_f32_16x16x32_bf16(av, opb2[c], a1, 0, 0, 0);
                else       a0 = __builtin_amdgcn_mfma_f32_16x16x32_bf16(av, opb2[c], a0, 0, 0, 0);
            }
            a0 = a0 + a1;
            int col = w * 16 + m16;
#pragma unroll
            for (int r = 0; r < 4; r++)
                hs[(q * 4 + r) * HST + col] = f2bf(a0[r]);
        }
        __syncthreads();
    }

    // final: wave w reduces row w
    {
        float s = 0.0f;
#pragma unroll
        for (int j = 0; j < 4; j++)
            s += bf2f(hs[w * HST + lane * 4 + j]) * Wo[lane * 4 + j];
#pragma unroll
        for (int off = 32; off > 0; off >>= 1) s += __shfl_down(s, off);
        if (lane == 0) out[rb + w] = s + bo[0];
    }
}

extern "C" void kernel_launch(void* const* d_in, const int* in_sizes, int n_in,
                              void* d_out, int out_size, void* d_ws, size_t ws_size,
                              hipStream_t stream)
{
    const float* x       = (const float*)d_in[0];
    const float* Wi      = (const float*)d_in[1];
    const float* bi      = (const float*)d_in[2];
    const float* in_proj = (const float*)d_in[3];
    const float* conv_w  = (const float*)d_in[4];
    const float* conv_b  = (const float*)d_in[5];
    const float* x_proj  = (const float*)d_in[6];
    const float* dt_w    = (const float*)d_in[7];
    const float* dt_b    = (const float*)d_in[8];
    // d_in[9] = A_log: dead (L==1, h0==0)
    const float* Dp      = (const float*)d_in[10];
    const float* out_pw  = (const float*)d_in[11];
    const float* Wo      = (const float*)d_in[12];
    const float* bo      = (const float*)d_in[13];

    short* ws   = (short*)d_ws;
    short* xpad = ws;                                   // 4096*256
    short* WiT  = xpad + (size_t)NB * DM;               // 256*256
    short* ipT  = WiT + (size_t)DM * DM;                // 12*1024*256
    short* opT  = ipT + (size_t)NL * 2 * DI * DM;       // 12*256*512
    short* xpT  = opT + (size_t)NL * DM * DI;           // 12*64*512
    float* dtwT = (float*)(xpT + (size_t)NL * 64 * DI); // 12*512*16 fp32

    dim3 blk(256);

    conv_x<<<dim3(NB * DM / 256), blk, 0, stream>>>(x, xpad);
    conv_wt_t<<<dim3(4, 4, 1), blk, 0, stream>>>(Wi, WiT, IN_D, DM, DM, DM);
    conv_wt_t<<<dim3(4, 16, NL), blk, 0, stream>>>(in_proj, ipT, DM, 2 * DI, DM, 2 * DI);
    conv_wt_t<<<dim3(8, 4, NL), blk, 0, stream>>>(out_pw, opT, DI, DM, DI, DM);
    conv_wt_t<<<dim3(8, 1, NL), blk, 0, stream>>>(x_proj, xpT, DI, XPN, DI, 64);
    conv_dtw<<<dim3(DI * DTR / 256, NL), blk, 0, stream>>>(dt_w, dtwT);

    mamba_all<<<dim3(NB / 16), dim3(1024), 0, stream>>>(
        xpad, WiT, bi, ipT, opT, xpT, dtwT,
        conv_w, conv_b, dt_b, Dp, Wo, bo, (float*)d_out);
}